// Round 1
// baseline (270.579 us; speedup 1.0000x reference)
//
#include <hip/hip_runtime.h>

// Capped simplex projection: per row, w = clip(z - tau, 0, u), sum(w) = 1.
// One wave (64 lanes) per row; 64 fp32 elements per lane in registers.

#define N_ASSETS 4096
#define N_SAMPLES 16384
#define MAX_W 0.02f
#define EPS 1e-7f
#define BISECT_ITERS 60

__device__ __forceinline__ float clip01u(float v) {
    // clamp(v, 0, MAX_W) -> v_med3_f32
    return fminf(fmaxf(v, 0.0f), MAX_W);
}

__global__ __launch_bounds__(256) void sparsemax_alloc_kernel(
    const float* __restrict__ x,
    const float* __restrict__ temperature,
    float* __restrict__ out) {

    const int wave = threadIdx.x >> 6;          // 4 waves per block
    const int lane = threadIdx.x & 63;
    const int row  = blockIdx.x * 4 + wave;
    if (row >= N_SAMPLES) return;

    const float4* xr   = reinterpret_cast<const float4*>(x + (size_t)row * N_ASSETS);
    float4*       outr = reinterpret_cast<float4*>(out + (size_t)row * N_ASSETS);

    const float rt = 1.0f / temperature[row];

    // Load 64 elements/lane as 16 coalesced float4s; z = x / temp.
    float4 z[16];
    #pragma unroll
    for (int k = 0; k < 16; ++k) {
        float4 v = xr[k * 64 + lane];
        z[k].x = v.x * rt; z[k].y = v.y * rt; z[k].z = v.z * rt; z[k].w = v.w * rt;
    }

    // Row min/max via per-lane then 64-lane butterfly.
    float mn = z[0].x, mx = z[0].x;
    #pragma unroll
    for (int k = 0; k < 16; ++k) {
        mn = fminf(mn, fminf(fminf(z[k].x, z[k].y), fminf(z[k].z, z[k].w)));
        mx = fmaxf(mx, fmaxf(fmaxf(z[k].x, z[k].y), fmaxf(z[k].z, z[k].w)));
    }
    #pragma unroll
    for (int m = 1; m <= 32; m <<= 1) {
        mn = fminf(mn, __shfl_xor(mn, m));
        mx = fmaxf(mx, __shfl_xor(mx, m));
    }

    float lo = mn - 1.0f;
    float hi = mx;

    // Bisection: sum clip(z - mid, 0, u) is nonincreasing in mid.
    for (int it = 0; it < BISECT_ITERS; ++it) {
        const float mid = 0.5f * (lo + hi);
        float s = 0.0f;
        #pragma unroll
        for (int k = 0; k < 16; ++k) {
            s += clip01u(z[k].x - mid);
            s += clip01u(z[k].y - mid);
            s += clip01u(z[k].z - mid);
            s += clip01u(z[k].w - mid);
        }
        #pragma unroll
        for (int m = 1; m <= 32; m <<= 1) s += __shfl_xor(s, m);
        const bool too_big = s > 1.0f;
        lo = too_big ? mid : lo;
        hi = too_big ? hi : mid;
    }
    const float tau0 = 0.5f * (lo + hi);

    // Active set: free = strictly interior, capped = at upper bound.
    const float ucut = MAX_W - EPS;
    float s_free = 0.0f, n_free = 0.0f, n_cap = 0.0f;
    #pragma unroll
    for (int k = 0; k < 16; ++k) {
        float zz[4] = {z[k].x, z[k].y, z[k].z, z[k].w};
        #pragma unroll
        for (int c = 0; c < 4; ++c) {
            const float w0 = clip01u(zz[c] - tau0);
            const bool fr = (w0 > EPS) && (w0 < ucut);
            const bool cp = (w0 >= ucut);
            s_free += fr ? zz[c] : 0.0f;
            n_free += fr ? 1.0f : 0.0f;
            n_cap  += cp ? 1.0f : 0.0f;
        }
    }
    #pragma unroll
    for (int m = 1; m <= 32; m <<= 1) {
        s_free += __shfl_xor(s_free, m);
        n_free += __shfl_xor(n_free, m);
        n_cap  += __shfl_xor(n_cap, m);
    }
    const float tau = (s_free + MAX_W * n_cap - 1.0f) / fmaxf(n_free, 1.0f);

    // Final write: free ? z - tau : (capped ? u : 0)
    #pragma unroll
    for (int k = 0; k < 16; ++k) {
        float zz[4] = {z[k].x, z[k].y, z[k].z, z[k].w};
        float4 o;
        float* oo = &o.x;
        #pragma unroll
        for (int c = 0; c < 4; ++c) {
            const float w0 = clip01u(zz[c] - tau0);
            const bool fr = (w0 > EPS) && (w0 < ucut);
            const bool cp = (w0 >= ucut);
            oo[c] = fr ? (zz[c] - tau) : (cp ? MAX_W : 0.0f);
        }
        outr[k * 64 + lane] = o;
    }
}

extern "C" void kernel_launch(void* const* d_in, const int* in_sizes, int n_in,
                              void* d_out, int out_size, void* d_ws, size_t ws_size,
                              hipStream_t stream) {
    const float* x    = (const float*)d_in[0];
    const float* temp = (const float*)d_in[1];
    float* out = (float*)d_out;
    (void)in_sizes; (void)n_in; (void)out_size; (void)d_ws; (void)ws_size;

    dim3 grid(N_SAMPLES / 4);   // 4 rows (waves) per 256-thread block
    dim3 block(256);
    hipLaunchKernelGGL(sparsemax_alloc_kernel, grid, block, 0, stream, x, temp, out);
}

// Round 2
// 188.647 us; speedup vs baseline: 1.4343x; 1.4343x over previous
//
#include <hip/hip_runtime.h>

// Capped simplex projection: per row, w = clip(z - tau, 0, u), sum(w) = 1.
// One wave (64 lanes) per row; 64 fp32 elements per lane in registers.
//
// R1 changes vs R0:
//  - BISECT_ITERS 60 -> 32 (interval resolves to ~4e-9; analytic tau refinement
//    makes output error O(delta) -- far under the 4e-4 threshold).
//  - 4 independent partial sums in the bisection inner loop to break the
//    64-deep serial FP add chain (compiler can't reassociate FP adds).

#define N_ASSETS 4096
#define N_SAMPLES 16384
#define MAX_W 0.02f
#define EPS 1e-7f
#define BISECT_ITERS 32

__device__ __forceinline__ float clip01u(float v) {
    // clamp(v, 0, MAX_W) -> v_med3_f32
    return fminf(fmaxf(v, 0.0f), MAX_W);
}

__global__ __launch_bounds__(256) void sparsemax_alloc_kernel(
    const float* __restrict__ x,
    const float* __restrict__ temperature,
    float* __restrict__ out) {

    const int wave = threadIdx.x >> 6;          // 4 waves per block
    const int lane = threadIdx.x & 63;
    const int row  = blockIdx.x * 4 + wave;
    if (row >= N_SAMPLES) return;

    const float4* xr   = reinterpret_cast<const float4*>(x + (size_t)row * N_ASSETS);
    float4*       outr = reinterpret_cast<float4*>(out + (size_t)row * N_ASSETS);

    const float rt = 1.0f / temperature[row];

    // Load 64 elements/lane as 16 coalesced float4s; z = x / temp.
    float4 z[16];
    #pragma unroll
    for (int k = 0; k < 16; ++k) {
        float4 v = xr[k * 64 + lane];
        z[k].x = v.x * rt; z[k].y = v.y * rt; z[k].z = v.z * rt; z[k].w = v.w * rt;
    }

    // Row min/max via per-lane then 64-lane butterfly.
    float mn = z[0].x, mx = z[0].x;
    #pragma unroll
    for (int k = 0; k < 16; ++k) {
        mn = fminf(mn, fminf(fminf(z[k].x, z[k].y), fminf(z[k].z, z[k].w)));
        mx = fmaxf(mx, fmaxf(fmaxf(z[k].x, z[k].y), fmaxf(z[k].z, z[k].w)));
    }
    #pragma unroll
    for (int m = 1; m <= 32; m <<= 1) {
        mn = fminf(mn, __shfl_xor(mn, m));
        mx = fmaxf(mx, __shfl_xor(mx, m));
    }

    float lo = mn - 1.0f;
    float hi = mx;

    // Bisection: sum clip(z - mid, 0, u) is nonincreasing in mid.
    for (int it = 0; it < BISECT_ITERS; ++it) {
        const float mid = 0.5f * (lo + hi);
        float s0 = 0.0f, s1 = 0.0f, s2 = 0.0f, s3 = 0.0f;
        #pragma unroll
        for (int k = 0; k < 16; k += 4) {
            s0 += clip01u(z[k+0].x - mid); s0 += clip01u(z[k+0].y - mid);
            s0 += clip01u(z[k+0].z - mid); s0 += clip01u(z[k+0].w - mid);
            s1 += clip01u(z[k+1].x - mid); s1 += clip01u(z[k+1].y - mid);
            s1 += clip01u(z[k+1].z - mid); s1 += clip01u(z[k+1].w - mid);
            s2 += clip01u(z[k+2].x - mid); s2 += clip01u(z[k+2].y - mid);
            s2 += clip01u(z[k+2].z - mid); s2 += clip01u(z[k+2].w - mid);
            s3 += clip01u(z[k+3].x - mid); s3 += clip01u(z[k+3].y - mid);
            s3 += clip01u(z[k+3].z - mid); s3 += clip01u(z[k+3].w - mid);
        }
        float s = (s0 + s1) + (s2 + s3);
        #pragma unroll
        for (int m = 1; m <= 32; m <<= 1) s += __shfl_xor(s, m);
        const bool too_big = s > 1.0f;
        lo = too_big ? mid : lo;
        hi = too_big ? hi : mid;
    }
    const float tau0 = 0.5f * (lo + hi);

    // Active set: free = strictly interior, capped = at upper bound.
    const float ucut = MAX_W - EPS;
    float sf0 = 0.0f, sf1 = 0.0f, nf0 = 0.0f, nf1 = 0.0f, nc0 = 0.0f, nc1 = 0.0f;
    #pragma unroll
    for (int k = 0; k < 16; k += 2) {
        float za[4] = {z[k].x, z[k].y, z[k].z, z[k].w};
        float zb[4] = {z[k+1].x, z[k+1].y, z[k+1].z, z[k+1].w};
        #pragma unroll
        for (int c = 0; c < 4; ++c) {
            const float wa = clip01u(za[c] - tau0);
            const bool fra = (wa > EPS) && (wa < ucut);
            const bool cpa = (wa >= ucut);
            sf0 += fra ? za[c] : 0.0f;
            nf0 += fra ? 1.0f : 0.0f;
            nc0 += cpa ? 1.0f : 0.0f;
            const float wb = clip01u(zb[c] - tau0);
            const bool frb = (wb > EPS) && (wb < ucut);
            const bool cpb = (wb >= ucut);
            sf1 += frb ? zb[c] : 0.0f;
            nf1 += frb ? 1.0f : 0.0f;
            nc1 += cpb ? 1.0f : 0.0f;
        }
    }
    float s_free = sf0 + sf1, n_free = nf0 + nf1, n_cap = nc0 + nc1;
    #pragma unroll
    for (int m = 1; m <= 32; m <<= 1) {
        s_free += __shfl_xor(s_free, m);
        n_free += __shfl_xor(n_free, m);
        n_cap  += __shfl_xor(n_cap, m);
    }
    const float tau = (s_free + MAX_W * n_cap - 1.0f) / fmaxf(n_free, 1.0f);

    // Final write: free ? z - tau : (capped ? u : 0)
    #pragma unroll
    for (int k = 0; k < 16; ++k) {
        float zz[4] = {z[k].x, z[k].y, z[k].z, z[k].w};
        float4 o;
        float* oo = &o.x;
        #pragma unroll
        for (int c = 0; c < 4; ++c) {
            const float w0 = clip01u(zz[c] - tau0);
            const bool fr = (w0 > EPS) && (w0 < ucut);
            const bool cp = (w0 >= ucut);
            oo[c] = fr ? (zz[c] - tau) : (cp ? MAX_W : 0.0f);
        }
        outr[k * 64 + lane] = o;
    }
}

extern "C" void kernel_launch(void* const* d_in, const int* in_sizes, int n_in,
                              void* d_out, int out_size, void* d_ws, size_t ws_size,
                              hipStream_t stream) {
    const float* x    = (const float*)d_in[0];
    const float* temp = (const float*)d_in[1];
    float* out = (float*)d_out;
    (void)in_sizes; (void)n_in; (void)out_size; (void)d_ws; (void)ws_size;

    dim3 grid(N_SAMPLES / 4);   // 4 rows (waves) per 256-thread block
    dim3 block(256);
    hipLaunchKernelGGL(sparsemax_alloc_kernel, grid, block, 0, stream, x, temp, out);
}